// Round 2
// baseline (1222.029 us; speedup 1.0000x reference)
//
#include <hip/hip_runtime.h>
#include <cstdint>
#include <cstddef>

#define SEQ      4096
#define DIMIN    2048
#define HID      4096
#define STATE    128
#define HEADS    64
#define HEAD_DIM 64
#define CONV_DIM 4352   // HID + 2*STATE
#define D_IN     8512
#define WROWS    8576   // in_proj rows padded to 67*128
#define XBCD_N   4480   // xBC+dt GEMM cols: 4416 padded to 35*128
#define CHUNK    256
#define NCHUNK   16

typedef __attribute__((ext_vector_type(8))) short short8;
typedef __attribute__((ext_vector_type(4))) float floatx4;
typedef __attribute__((ext_vector_type(4))) unsigned int uintx4;

__device__ __forceinline__ unsigned short f2bf(float f) {
    union { float f; unsigned int u; } v; v.f = f;
    unsigned int r = v.u + 0x7FFFu + ((v.u >> 16) & 1u);
    return (unsigned short)(r >> 16);
}
__device__ __forceinline__ float bf2f(unsigned short u) {
    union { unsigned int u; float f; } v; v.u = ((unsigned int)u) << 16;
    return v.f;
}

// ---------------- fp32 -> bf16 convert (with zero tail padding) ----------------
__global__ void k_convert(const float* __restrict__ src, unsigned short* __restrict__ dst,
                          long n, long nsrc) {
    long i = (long)blockIdx.x * blockDim.x + threadIdx.x;
    if (i >= n) return;
    float v = (i < nsrc) ? src[i] : 0.f;
    dst[i] = f2bf(v);
}

// ---------------- bf16 MFMA GEMM: C[M,N] = A[M,K] * B[N,K]^T ----------------
// BM=BN=128, BK=64, 4 waves (2x2), each wave 64x64 via 4x4 of 16x16x32 MFMA.
// BF16OUT=1 writes bf16 C (optional fp32 side-channel for 64 cols at auxc0).
#define BM 128
#define BN 128
#define BK 64
#define LDT 72   // padded LDS row stride (ushorts)

template <int BF16OUT>
__global__ __launch_bounds__(256) void k_gemm(
    const unsigned short* __restrict__ A, const unsigned short* __restrict__ B,
    void* __restrict__ Cout, int K, int ldc, float* __restrict__ aux, int auxc0)
{
    __shared__ __attribute__((aligned(16))) unsigned short As[BM * LDT];
    __shared__ __attribute__((aligned(16))) unsigned short Bs[BN * LDT];
    const int tid = threadIdx.x;
    const int bm = blockIdx.y, bn = blockIdx.x;
    const int wid = tid >> 6, lane = tid & 63;
    const int wm = (wid >> 1) * 64, wn = (wid & 1) * 64;
    const int lrow = lane & 15;
    const int lk = (lane >> 4) * 8;

    floatx4 acc[4][4];
#pragma unroll
    for (int i = 0; i < 4; ++i)
#pragma unroll
        for (int j = 0; j < 4; ++j) acc[i][j] = (floatx4){0.f, 0.f, 0.f, 0.f};

    const long a_base = (long)bm * BM * K;
    const long b_base = (long)bn * BN * K;

    for (int k0 = 0; k0 < K; k0 += BK) {
#pragma unroll
        for (int i = 0; i < 4; ++i) {
            int c = tid + i * 256;
            int row = c >> 3;
            int col = (c & 7) * 8;
            *(uintx4*)&As[row * LDT + col] = *(const uintx4*)&A[a_base + (long)row * K + k0 + col];
            *(uintx4*)&Bs[row * LDT + col] = *(const uintx4*)&B[b_base + (long)row * K + k0 + col];
        }
        __syncthreads();
#pragma unroll
        for (int kk = 0; kk < BK; kk += 32) {
            short8 af[4], bfr[4];
#pragma unroll
            for (int i = 0; i < 4; ++i)
                af[i] = *(const short8*)&As[(wm + i * 16 + lrow) * LDT + kk + lk];
#pragma unroll
            for (int j = 0; j < 4; ++j)
                bfr[j] = *(const short8*)&Bs[(wn + j * 16 + lrow) * LDT + kk + lk];
#pragma unroll
            for (int i = 0; i < 4; ++i)
#pragma unroll
                for (int j = 0; j < 4; ++j)
                    acc[i][j] = __builtin_amdgcn_mfma_f32_16x16x32_bf16(af[i], bfr[j], acc[i][j], 0, 0, 0);
        }
        __syncthreads();
    }
    const int rcol = lane & 15;
    const int rrow = (lane >> 4) * 4;
#pragma unroll
    for (int i = 0; i < 4; ++i)
#pragma unroll
        for (int j = 0; j < 4; ++j) {
            int col = bn * BN + wn + j * 16 + rcol;
#pragma unroll
            for (int r = 0; r < 4; ++r) {
                int row = bm * BM + wm + i * 16 + rrow + r;
                float v = acc[i][j][r];
                if (BF16OUT) {
                    ((unsigned short*)Cout)[(long)row * ldc + col] = f2bf(v);
                    if (aux && col >= auxc0 && col < auxc0 + 64)
                        aux[(long)row * 64 + (col - auxc0)] = v;
                } else {
                    ((float*)Cout)[(long)row * ldc + col] = v;
                }
            }
        }
}

// ---------------- causal conv1d (k=4) + SiLU, bf16 in/out ----------------
__global__ void k_conv(const unsigned short* __restrict__ xbcd, const float* __restrict__ convw,
                       unsigned short* __restrict__ xc) {
    long i = (long)blockIdx.x * 256 + threadIdx.x;
    if (i >= (long)SEQ * CONV_DIM) return;
    int c = (int)(i % CONV_DIM);
    int s = (int)(i / CONV_DIM);
    float w0 = convw[c * 4 + 0], w1 = convw[c * 4 + 1];
    float w2 = convw[c * 4 + 2], w3 = convw[c * 4 + 3];
    float acc = bf2f(xbcd[(long)s * XBCD_N + c]) * w3;
    if (s >= 1) acc += bf2f(xbcd[(long)(s - 1) * XBCD_N + c]) * w2;
    if (s >= 2) acc += bf2f(xbcd[(long)(s - 2) * XBCD_N + c]) * w1;
    if (s >= 3) acc += bf2f(xbcd[(long)(s - 3) * XBCD_N + c]) * w0;
    float sl = acc / (1.f + __expf(-acc));
    xc[i] = f2bf(sl);
}

// ---------------- dt = softplus(dtraw+bias), dA = dt*A, per-chunk inclusive cumsum ----------------
__global__ __launch_bounds__(256) void k_dt(const float* __restrict__ dtraw,
        const float* __restrict__ dt_bias, const float* __restrict__ A_log,
        float* __restrict__ dtv, float* __restrict__ dAc, float* __restrict__ dAlast)
{
    int c = blockIdx.x, h = blockIdx.y;
    int l = threadIdx.x;
    __shared__ float sh[CHUNK];
    float v = dtraw[(long)(c * CHUNK + l) * 64 + h] + dt_bias[h];
    float dt = (v > 20.f) ? v : log1pf(__expf(v));
    float Ah = -__expf(A_log[h]);
    float dA = dt * Ah;
    sh[l] = dA;
    __syncthreads();
    float x = dA;
#pragma unroll
    for (int off = 1; off < CHUNK; off <<= 1) {
        float t = (l >= off) ? sh[l - off] : 0.f;
        __syncthreads();
        x += t;
        sh[l] = x;
        __syncthreads();
    }
    dtv[(long)(c * CHUNK + l) * HEADS + h] = dt;
    dAc[(long)(c * CHUNK + l) * HEADS + h] = x;
    if (l == CHUNK - 1) dAlast[c * HEADS + h] = x;
}

// ---------------- G[c][l][s] = C[l] . B[s] ----------------
__global__ __launch_bounds__(256) void k_G(const unsigned short* __restrict__ xc, float* __restrict__ G) {
    int c = blockIdx.x, l = blockIdx.y;
    int s = threadIdx.x;
    __shared__ float Csh[STATE];
    if (s < STATE) Csh[s] = bf2f(xc[(long)(c * CHUNK + l) * CONV_DIM + HID + STATE + s]);
    __syncthreads();
    const unsigned short* Brow = xc + (long)(c * CHUNK + s) * CONV_DIM + HID;
    float acc = 0.f;
#pragma unroll 8
    for (int n = 0; n < STATE; ++n) acc += Csh[n] * bf2f(Brow[n]);
    G[((long)c * CHUNK + l) * CHUNK + s] = acc;
}

// ---------------- states[c,h,p,n] = sum_l B[l,n]*exp(dAlast-dAc[l])*dt[l]*xh[l,p] ----------------
__global__ __launch_bounds__(256) void k_states(
    const unsigned short* __restrict__ xc, const float* __restrict__ dtv,
    const float* __restrict__ dAc, const float* __restrict__ dAlast,
    float* __restrict__ states)
{
    int c = blockIdx.x, h = blockIdx.y;
    int t = threadIdx.x;
    __shared__ float xs[64][64];
    __shared__ float dA_sh[CHUNK], dt_sh[CHUNK];
    long base_s = (long)c * CHUNK;
    dA_sh[t] = dAc[(base_s + t) * HEADS + h];
    dt_sh[t] = dtv[(base_s + t) * HEADS + h];
    __syncthreads();
    float dAl = dAlast[c * HEADS + h];
    int p0 = t >> 5;
    int n0 = t & 31;
    float acc[8][4];
#pragma unroll
    for (int ip = 0; ip < 8; ++ip)
#pragma unroll
        for (int j = 0; j < 4; ++j) acc[ip][j] = 0.f;

    for (int lb = 0; lb < 4; ++lb) {
#pragma unroll
        for (int i = 0; i < 16; ++i) {
            int e = t + i * 256;
            int r = e >> 6, pcol = e & 63;
            float ds = __expf(dAl - dA_sh[lb * 64 + r]) * dt_sh[lb * 64 + r];
            xs[r][pcol] = bf2f(xc[(base_s + lb * 64 + r) * CONV_DIM + h * HEAD_DIM + pcol]) * ds;
        }
        __syncthreads();
        for (int lp = 0; lp < 64; ++lp) {
            const unsigned short* Brow = xc + (base_s + lb * 64 + lp) * CONV_DIM + HID;
            float bv[4];
#pragma unroll
            for (int j = 0; j < 4; ++j) bv[j] = bf2f(Brow[n0 + 32 * j]);
#pragma unroll
            for (int ip = 0; ip < 8; ++ip) {
                float xv = xs[lp][p0 + 8 * ip];
#pragma unroll
                for (int j = 0; j < 4; ++j) acc[ip][j] += xv * bv[j];
            }
        }
        __syncthreads();
    }
    float* Sb = states + (long)(c * HEADS + h) * HEAD_DIM * STATE;
#pragma unroll
    for (int ip = 0; ip < 8; ++ip)
#pragma unroll
        for (int j = 0; j < 4; ++j)
            Sb[(p0 + 8 * ip) * STATE + n0 + 32 * j] = acc[ip][j];
}

// ---------------- sequential chunk-state scan (in place: states[c] := prev state) ----------------
__global__ void k_scan(float* __restrict__ states, const float* __restrict__ dAlast) {
    int t = blockIdx.x * 256 + threadIdx.x;
    if (t >= HEADS * HEAD_DIM * STATE) return;
    int h = t >> 13;
    const long stride = (long)HEADS * HEAD_DIM * STATE;
    float carry = 0.f;
    for (int c = 0; c < NCHUNK; ++c) {
        float s = states[c * stride + t];
        float dec = __expf(dAlast[c * HEADS + h]);
        states[c * stride + t] = carry;
        carry = carry * dec + s;
    }
}

// ---------------- y = y_off + y_diag + D*x  (merged), bf16 out ----------------
__global__ __launch_bounds__(256) void k_ssd_y(
    const unsigned short* __restrict__ xc, const float* __restrict__ G,
    const float* __restrict__ dtv, const float* __restrict__ dAc,
    const float* __restrict__ prev, const float* __restrict__ Dp,
    unsigned short* __restrict__ y)
{
    int c = blockIdx.x, h = blockIdx.y;
    int l = threadIdx.x;
    __shared__ __attribute__((aligned(16))) float psh[64 * 128];
    __shared__ float xdt_sh[64][64];
    __shared__ float dA_sh[CHUNK];
    __shared__ float dt_sh[CHUNK];
    long base_s = (long)c * CHUNK;
    dA_sh[l] = dAc[(base_s + l) * HEADS + h];
    dt_sh[l] = dtv[(base_s + l) * HEADS + h];
#pragma unroll
    for (int i = 0; i < 32; ++i) {
        int e = l + i * 256;
        psh[e] = prev[(long)(c * HEADS + h) * HEAD_DIM * STATE + e];
    }
    __syncthreads();
    float myA = dA_sh[l];
    float eA = __expf(myA);
    float acc[64];
#pragma unroll
    for (int p = 0; p < 64; ++p) acc[p] = 0.f;

    // off term: acc[p] = eA * sum_n C[l,n] * prev[p,n]
    const unsigned short* Crow = xc + (base_s + l) * CONV_DIM + HID + STATE;
    for (int nb = 0; nb < 4; ++nb) {
        float cf[32];
#pragma unroll
        for (int j = 0; j < 32; ++j) cf[j] = bf2f(Crow[nb * 32 + j]) * eA;
        for (int p = 0; p < 64; ++p) {
            float s = 0.f;
#pragma unroll
            for (int j = 0; j < 32; j += 4) {
                float4 v = *(const float4*)&psh[p * 128 + nb * 32 + j];
                s += cf[j] * v.x + cf[j + 1] * v.y + cf[j + 2] * v.z + cf[j + 3] * v.w;
            }
            acc[p] += s;
        }
    }

    // diag term
    const float* Grow = G + ((long)c * CHUNK + l) * CHUNK;
    for (int sb = 0; sb < 4; ++sb) {
#pragma unroll
        for (int i = 0; i < 16; ++i) {
            int e = threadIdx.x + i * 256;
            int r = e >> 6, pcol = e & 63;
            xdt_sh[r][pcol] = bf2f(xc[(base_s + sb * 64 + r) * CONV_DIM + h * HEAD_DIM + pcol]) * dt_sh[sb * 64 + r];
        }
        __syncthreads();
        if (l >= sb * 64) {
            int send = min(63, l - sb * 64);
            for (int sp = 0; sp <= send; ++sp) {
                int s = sb * 64 + sp;
                float coeff = Grow[s] * __expf(myA - dA_sh[s]);
#pragma unroll
                for (int p = 0; p < 64; ++p) acc[p] += coeff * xdt_sh[sp][p];
            }
        }
        __syncthreads();
    }
    float Dh = Dp[h];
    const unsigned short* xrow = xc + (base_s + l) * CONV_DIM + h * HEAD_DIM;
    unsigned short* yrow = y + (base_s + l) * (long)HID + h * HEAD_DIM;
#pragma unroll
    for (int p = 0; p < 64; ++p) yrow[p] = f2bf(acc[p] + Dh * bf2f(xrow[p]));
}

// ---------------- gate with silu(z), RMSNorm, bf16 out ----------------
__global__ __launch_bounds__(256) void k_norm(
    const unsigned short* __restrict__ y, const unsigned short* __restrict__ z,
    const float* __restrict__ norm_w, unsigned short* __restrict__ yb)
{
    int s = blockIdx.x;
    int t = threadIdx.x;
    const unsigned short* yrow = y + (long)s * HID;
    const unsigned short* zrow = z + (long)s * HID;
    float vals[16];
    float ss = 0.f;
#pragma unroll
    for (int i = 0; i < 16; ++i) {
        int j = t + i * 256;
        float yv = bf2f(yrow[j]);
        float zv = bf2f(zrow[j]);
        float g = yv * (zv / (1.f + __expf(-zv)));
        vals[i] = g;
        ss += g * g;
    }
#pragma unroll
    for (int off = 32; off > 0; off >>= 1) ss += __shfl_down(ss, off);
    __shared__ float wsum[4];
    int lane = t & 63, wid = t >> 6;
    if (lane == 0) wsum[wid] = ss;
    __syncthreads();
    float total = wsum[0] + wsum[1] + wsum[2] + wsum[3];
    float scale = rsqrtf(total / HID + 1e-5f);
#pragma unroll
    for (int i = 0; i < 16; ++i) {
        int j = t + i * 256;
        yb[(long)s * HID + j] = f2bf(vals[i] * scale * norm_w[j]);
    }
}

// ---------------- launch ----------------
extern "C" void kernel_launch(void* const* d_in, const int* in_sizes, int n_in,
                              void* d_out, int out_size, void* d_ws, size_t ws_size,
                              hipStream_t stream) {
    const float* x          = (const float*)d_in[0];
    const float* in_proj_w  = (const float*)d_in[1];
    const float* conv_w     = (const float*)d_in[2];
    const float* dt_bias    = (const float*)d_in[3];
    const float* A_log      = (const float*)d_in[4];
    const float* Dp         = (const float*)d_in[5];
    const float* norm_w     = (const float*)d_in[6];
    const float* out_proj_w = (const float*)d_in[7];
    char* ws = (char*)d_ws;

    // workspace layout (bytes) — total 131,600,384
    const size_t off_xb    = 0;                                         // 16,777,216 (bf16 x)
    const size_t off_wbin  = off_xb    + (size_t)SEQ * DIMIN * 2;       // 35,127,296 (bf16 in_proj, padded)
    const size_t off_xbcd  = off_wbin  + (size_t)WROWS * DIMIN * 2;     // 36,700,160 (bf16 xBC+dt; later y bf16)
    const size_t off_xc    = off_xbcd  + (size_t)SEQ * XBCD_N * 2;      // 35,651,584 (bf16 conv out; later yb)
    const size_t off_dtraw = off_xc    + (size_t)SEQ * CONV_DIM * 2;    // 1,048,576 (fp32 dt side-channel)
    const size_t off_dtv   = off_dtraw + (size_t)SEQ * 64 * 4;
    const size_t off_dAc   = off_dtv   + (size_t)SEQ * HEADS * 4;
    const size_t off_dAl   = off_dAc   + (size_t)SEQ * HEADS * 4;
    const size_t off_G     = off_dAl   + (size_t)NCHUNK * HEADS * 4;
    const size_t needed    = off_G     + (size_t)NCHUNK * CHUNK * CHUNK * 4;
    if (ws_size < needed) return;   // diagnostic: clean numeric failure instead of fault

    unsigned short* xb    = (unsigned short*)(ws + off_xb);
    unsigned short* wbin  = (unsigned short*)(ws + off_wbin);
    unsigned short* xbcd  = (unsigned short*)(ws + off_xbcd);
    unsigned short* xc    = (unsigned short*)(ws + off_xc);
    float* dtraw = (float*)(ws + off_dtraw);
    float* dtv   = (float*)(ws + off_dtv);
    float* dAc   = (float*)(ws + off_dAc);
    float* dAl   = (float*)(ws + off_dAl);
    float* G     = (float*)(ws + off_G);

    // d_out doubles as scratch: states fp32 -> z bf16 -> final out fp32 (stream-ordered)
    float* states      = (float*)d_out;
    unsigned short* z  = (unsigned short*)d_out;
    unsigned short* y  = xbcd;                       // aliases dead xBCdt, row stride HID
    unsigned short* yb = xc;                         // aliases dead xc
    unsigned short* wob = wbin;                      // aliases dead wbin

    // 1. converts
    { long n = (long)SEQ * DIMIN;
      k_convert<<<(unsigned)((n + 255) / 256), 256, 0, stream>>>(x, xb, n, n); }
    { long n = (long)WROWS * DIMIN, nsrc = (long)D_IN * DIMIN;
      k_convert<<<(unsigned)((n + 255) / 256), 256, 0, stream>>>(in_proj_w, wbin, n, nsrc); }
    // 2. GEMM1b: xBCdt[SEQ,4480] = xb @ wbin[4096:8576]^T  (+ fp32 dt side-channel)
    k_gemm<1><<<dim3(XBCD_N / BN, SEQ / BM), 256, 0, stream>>>(
        xb, wbin + (size_t)HID * DIMIN, (void*)xbcd, DIMIN, XBCD_N, dtraw, 4352);
    // 3. conv1d + silu
    { long n = (long)SEQ * CONV_DIM;
      k_conv<<<(unsigned)((n + 255) / 256), 256, 0, stream>>>(xbcd, conv_w, xc); }
    // 4. dt/softplus + per-chunk cumsum
    k_dt<<<dim3(NCHUNK, HEADS), 256, 0, stream>>>(dtraw, dt_bias, A_log, dtv, dAc, dAl);
    // 5. G = C.B^T
    k_G<<<dim3(NCHUNK, CHUNK), 256, 0, stream>>>(xc, G);
    // 6. per-chunk states -> d_out
    k_states<<<dim3(NCHUNK, HEADS), 256, 0, stream>>>(xc, dtv, dAc, dAl, states);
    // 7. sequential scan over chunks (in place)
    k_scan<<<(HEADS * HEAD_DIM * STATE) / 256, 256, 0, stream>>>(states, dAl);
    // 8. y = off + diag + D*x  -> y (bf16, over dead xBCdt)
    k_ssd_y<<<dim3(NCHUNK, HEADS), 256, 0, stream>>>(xc, G, dtv, dAc, states, Dp, y);
    // 9. GEMM-z: z[SEQ,HID] = xb @ wbin[0:4096]^T -> bf16 into d_out (states dead)
    k_gemm<1><<<dim3(HID / BN, SEQ / BM), 256, 0, stream>>>(
        xb, wbin, (void*)z, DIMIN, HID, nullptr, 0);
    // 10. gate + RMSNorm -> yb (over dead xc)
    k_norm<<<SEQ, 256, 0, stream>>>(y, z, norm_w, yb);
    // 11. convert out_proj -> wob (over dead wbin)
    { long n = (long)DIMIN * HID;
      k_convert<<<(unsigned)((n + 255) / 256), 256, 0, stream>>>(out_proj_w, wob, n, n); }
    // 12. GEMM2: out[SEQ,DIMIN] = yb @ wob^T -> fp32 d_out (z dead)
    k_gemm<0><<<dim3(DIMIN / BN, SEQ / BM), 256, 0, stream>>>(
        yb, wob, d_out, HID, DIMIN, nullptr, 0);
}

// Round 3
// 988.525 us; speedup vs baseline: 1.2362x; 1.2362x over previous
//
#include <hip/hip_runtime.h>
#include <cstdint>
#include <cstddef>

#define SEQ      4096
#define DIMIN    2048
#define HID      4096
#define STATE    128
#define HEADS    64
#define HEAD_DIM 64
#define CONV_DIM 4352   // HID + 2*STATE
#define D_IN     8512
#define WROWS    8576   // in_proj rows padded to 67*128
#define XBCD_N   4480   // xBC+dt GEMM cols: 4416 padded to 35*128
#define CHUNK    256
#define NCHUNK   16

typedef __attribute__((ext_vector_type(8))) short short8;
typedef __attribute__((ext_vector_type(4))) float floatx4;
typedef __attribute__((ext_vector_type(4))) unsigned int uintx4;

__device__ __forceinline__ unsigned short f2bf(float f) {
    union { float f; unsigned int u; } v; v.f = f;
    unsigned int r = v.u + 0x7FFFu + ((v.u >> 16) & 1u);
    return (unsigned short)(r >> 16);
}
__device__ __forceinline__ float bf2f(unsigned short u) {
    union { unsigned int u; float f; } v; v.u = ((unsigned int)u) << 16;
    return v.f;
}

// ---------------- fp32 -> bf16 convert (with zero tail padding) ----------------
__global__ void k_convert(const float* __restrict__ src, unsigned short* __restrict__ dst,
                          long n, long nsrc) {
    long i = (long)blockIdx.x * blockDim.x + threadIdx.x;
    if (i >= n) return;
    float v = (i < nsrc) ? src[i] : 0.f;
    dst[i] = f2bf(v);
}

// ---------------- bf16 MFMA GEMM: C[M,N] = A[M,K] * B[N,K]^T ----------------
#define BM 128
#define BN 128
#define BK 64
#define LDT 72   // padded LDS row stride (ushorts)

template <int BF16OUT>
__global__ __launch_bounds__(256) void k_gemm(
    const unsigned short* __restrict__ A, const unsigned short* __restrict__ B,
    void* __restrict__ Cout, int K, int ldc, float* __restrict__ aux, int auxc0)
{
    __shared__ __attribute__((aligned(16))) unsigned short As[BM * LDT];
    __shared__ __attribute__((aligned(16))) unsigned short Bs[BN * LDT];
    const int tid = threadIdx.x;
    const int bm = blockIdx.y, bn = blockIdx.x;
    const int wid = tid >> 6, lane = tid & 63;
    const int wm = (wid >> 1) * 64, wn = (wid & 1) * 64;
    const int lrow = lane & 15;
    const int lk = (lane >> 4) * 8;

    floatx4 acc[4][4];
#pragma unroll
    for (int i = 0; i < 4; ++i)
#pragma unroll
        for (int j = 0; j < 4; ++j) acc[i][j] = (floatx4){0.f, 0.f, 0.f, 0.f};

    const long a_base = (long)bm * BM * K;
    const long b_base = (long)bn * BN * K;

    for (int k0 = 0; k0 < K; k0 += BK) {
#pragma unroll
        for (int i = 0; i < 4; ++i) {
            int c = tid + i * 256;
            int row = c >> 3;
            int col = (c & 7) * 8;
            *(uintx4*)&As[row * LDT + col] = *(const uintx4*)&A[a_base + (long)row * K + k0 + col];
            *(uintx4*)&Bs[row * LDT + col] = *(const uintx4*)&B[b_base + (long)row * K + k0 + col];
        }
        __syncthreads();
#pragma unroll
        for (int kk = 0; kk < BK; kk += 32) {
            short8 af[4], bfr[4];
#pragma unroll
            for (int i = 0; i < 4; ++i)
                af[i] = *(const short8*)&As[(wm + i * 16 + lrow) * LDT + kk + lk];
#pragma unroll
            for (int j = 0; j < 4; ++j)
                bfr[j] = *(const short8*)&Bs[(wn + j * 16 + lrow) * LDT + kk + lk];
#pragma unroll
            for (int i = 0; i < 4; ++i)
#pragma unroll
                for (int j = 0; j < 4; ++j)
                    acc[i][j] = __builtin_amdgcn_mfma_f32_16x16x32_bf16(af[i], bfr[j], acc[i][j], 0, 0, 0);
        }
        __syncthreads();
    }
    const int rcol = lane & 15;
    const int rrow = (lane >> 4) * 4;
#pragma unroll
    for (int i = 0; i < 4; ++i)
#pragma unroll
        for (int j = 0; j < 4; ++j) {
            int col = bn * BN + wn + j * 16 + rcol;
#pragma unroll
            for (int r = 0; r < 4; ++r) {
                int row = bm * BM + wm + i * 16 + rrow + r;
                float v = acc[i][j][r];
                if (BF16OUT) {
                    ((unsigned short*)Cout)[(long)row * ldc + col] = f2bf(v);
                    if (aux && col >= auxc0 && col < auxc0 + 64)
                        aux[(long)row * 64 + (col - auxc0)] = v;
                } else {
                    ((float*)Cout)[(long)row * ldc + col] = v;
                }
            }
        }
}

// ---------------- causal conv1d (k=4) + SiLU, bf16 in/out ----------------
__global__ void k_conv(const unsigned short* __restrict__ xbcd, const float* __restrict__ convw,
                       unsigned short* __restrict__ xc) {
    long i = (long)blockIdx.x * 256 + threadIdx.x;
    if (i >= (long)SEQ * CONV_DIM) return;
    int c = (int)(i % CONV_DIM);
    int s = (int)(i / CONV_DIM);
    float w0 = convw[c * 4 + 0], w1 = convw[c * 4 + 1];
    float w2 = convw[c * 4 + 2], w3 = convw[c * 4 + 3];
    float acc = bf2f(xbcd[(long)s * XBCD_N + c]) * w3;
    if (s >= 1) acc += bf2f(xbcd[(long)(s - 1) * XBCD_N + c]) * w2;
    if (s >= 2) acc += bf2f(xbcd[(long)(s - 2) * XBCD_N + c]) * w1;
    if (s >= 3) acc += bf2f(xbcd[(long)(s - 3) * XBCD_N + c]) * w0;
    float sl = acc / (1.f + __expf(-acc));
    xc[i] = f2bf(sl);
}

// ---------------- dt = softplus(dtraw+bias), dA = dt*A, per-chunk inclusive cumsum ----------------
__global__ __launch_bounds__(256) void k_dt(const float* __restrict__ dtraw,
        const float* __restrict__ dt_bias, const float* __restrict__ A_log,
        float* __restrict__ dtv, float* __restrict__ dAc, float* __restrict__ dAlast)
{
    int c = blockIdx.x, h = blockIdx.y;
    int l = threadIdx.x;
    __shared__ float sh[CHUNK];
    float v = dtraw[(long)(c * CHUNK + l) * 64 + h] + dt_bias[h];
    float dt = (v > 20.f) ? v : log1pf(__expf(v));
    float Ah = -__expf(A_log[h]);
    float dA = dt * Ah;
    sh[l] = dA;
    __syncthreads();
    float x = dA;
#pragma unroll
    for (int off = 1; off < CHUNK; off <<= 1) {
        float t = (l >= off) ? sh[l - off] : 0.f;
        __syncthreads();
        x += t;
        sh[l] = x;
        __syncthreads();
    }
    dtv[(long)(c * CHUNK + l) * HEADS + h] = dt;
    dAc[(long)(c * CHUNK + l) * HEADS + h] = x;
    if (l == CHUNK - 1) dAlast[c * HEADS + h] = x;
}

// ---------------- G[c][l][s] = C[l] . B[s] ----------------
__global__ __launch_bounds__(256) void k_G(const unsigned short* __restrict__ xc, float* __restrict__ G) {
    int c = blockIdx.x, l = blockIdx.y;
    int s = threadIdx.x;
    __shared__ float Csh[STATE];
    if (s < STATE) Csh[s] = bf2f(xc[(long)(c * CHUNK + l) * CONV_DIM + HID + STATE + s]);
    __syncthreads();
    const unsigned short* Brow = xc + (long)(c * CHUNK + s) * CONV_DIM + HID;
    float acc = 0.f;
#pragma unroll
    for (int n = 0; n < STATE; n += 8) {
        short8 b8 = *(const short8*)&Brow[n];
#pragma unroll
        for (int j = 0; j < 8; ++j)
            acc += Csh[n + j] * bf2f((unsigned short)b8[j]);
    }
    G[((long)c * CHUNK + l) * CHUNK + s] = acc;
}

// ---------------- states[c,h,p,n] = sum_l B[l,n]*exp(dAlast-dAc[l])*dt[l]*xh[l,p] ----------------
__global__ __launch_bounds__(256) void k_states(
    const unsigned short* __restrict__ xc, const float* __restrict__ dtv,
    const float* __restrict__ dAc, const float* __restrict__ dAlast,
    float* __restrict__ states)
{
    int c = blockIdx.x, h = blockIdx.y;
    int t = threadIdx.x;
    __shared__ float xs[64][64];
    __shared__ float dA_sh[CHUNK], dt_sh[CHUNK];
    long base_s = (long)c * CHUNK;
    dA_sh[t] = dAc[(base_s + t) * HEADS + h];
    dt_sh[t] = dtv[(base_s + t) * HEADS + h];
    __syncthreads();
    float dAl = dAlast[c * HEADS + h];
    int p0 = t >> 5;
    int n0 = t & 31;
    float acc[8][4];
#pragma unroll
    for (int ip = 0; ip < 8; ++ip)
#pragma unroll
        for (int j = 0; j < 4; ++j) acc[ip][j] = 0.f;

    for (int lb = 0; lb < 4; ++lb) {
#pragma unroll
        for (int i = 0; i < 16; ++i) {
            int e = t + i * 256;
            int r = e >> 6, pcol = e & 63;
            float ds = __expf(dAl - dA_sh[lb * 64 + r]) * dt_sh[lb * 64 + r];
            xs[r][pcol] = bf2f(xc[(base_s + lb * 64 + r) * CONV_DIM + h * HEAD_DIM + pcol]) * ds;
        }
        __syncthreads();
        for (int lp = 0; lp < 64; ++lp) {
            const unsigned short* Brow = xc + (base_s + lb * 64 + lp) * CONV_DIM + HID;
            float bv[4];
#pragma unroll
            for (int j = 0; j < 4; ++j) bv[j] = bf2f(Brow[n0 + 32 * j]);
#pragma unroll
            for (int ip = 0; ip < 8; ++ip) {
                float xv = xs[lp][p0 + 8 * ip];
#pragma unroll
                for (int j = 0; j < 4; ++j) acc[ip][j] += xv * bv[j];
            }
        }
        __syncthreads();
    }
    float* Sb = states + (long)(c * HEADS + h) * HEAD_DIM * STATE;
#pragma unroll
    for (int ip = 0; ip < 8; ++ip)
#pragma unroll
        for (int j = 0; j < 4; ++j)
            Sb[(p0 + 8 * ip) * STATE + n0 + 32 * j] = acc[ip][j];
}

// ---------------- sequential chunk-state scan (in place: states[c] := prev state) ----------------
__global__ void k_scan(float* __restrict__ states, const float* __restrict__ dAlast) {
    int t = blockIdx.x * 256 + threadIdx.x;
    if (t >= HEADS * HEAD_DIM * STATE) return;
    int h = t >> 13;
    const long stride = (long)HEADS * HEAD_DIM * STATE;
    float carry = 0.f;
    for (int c = 0; c < NCHUNK; ++c) {
        float s = states[c * stride + t];
        float dec = __expf(dAlast[c * HEADS + h]);
        states[c * stride + t] = carry;
        carry = carry * dec + s;
    }
}

// ---------------- y = y_off + y_diag + D*x  (merged), bf16 out ----------------
// acc[64] MUST stay in VGPRs: every loop touching acc[] is fully unrolled
// (round-2 version left the off-term p-loop rolled -> dynamic indexing ->
//  scratch spill -> 734 MB HBM traffic/dispatch and 525 us).
__global__ __launch_bounds__(256) void k_ssd_y(
    const unsigned short* __restrict__ xc, const float* __restrict__ G,
    const float* __restrict__ dtv, const float* __restrict__ dAc,
    const float* __restrict__ prev, const float* __restrict__ Dp,
    unsigned short* __restrict__ y)
{
    int c = blockIdx.x, h = blockIdx.y;
    int l = threadIdx.x;
    __shared__ __attribute__((aligned(16))) float psh[64 * 128];
    __shared__ float xdt_sh[64][64];
    __shared__ float dA_sh[CHUNK];
    __shared__ float dt_sh[CHUNK];
    long base_s = (long)c * CHUNK;
    dA_sh[l] = dAc[(base_s + l) * HEADS + h];
    dt_sh[l] = dtv[(base_s + l) * HEADS + h];
#pragma unroll
    for (int i = 0; i < 32; ++i) {
        int e = l + i * 256;
        psh[e] = prev[(long)(c * HEADS + h) * HEAD_DIM * STATE + e];
    }
    __syncthreads();
    float myA = dA_sh[l];
    float eA = __expf(myA);
    float acc[64];
#pragma unroll
    for (int p = 0; p < 64; ++p) acc[p] = 0.f;

    // off term: acc[p] = eA * sum_n C[l,n] * prev[p,n]
    const unsigned short* Crow = xc + (base_s + l) * CONV_DIM + HID + STATE;
    for (int nb = 0; nb < 4; ++nb) {
        float cf[32];
#pragma unroll
        for (int j = 0; j < 32; ++j) cf[j] = bf2f(Crow[nb * 32 + j]) * eA;
#pragma unroll
        for (int p = 0; p < 64; ++p) {
            float s = 0.f;
#pragma unroll
            for (int j = 0; j < 32; j += 4) {
                float4 v = *(const float4*)&psh[p * 128 + nb * 32 + j];
                s += cf[j] * v.x + cf[j + 1] * v.y + cf[j + 2] * v.z + cf[j + 3] * v.w;
            }
            acc[p] += s;
        }
    }

    // diag term
    const float* Grow = G + ((long)c * CHUNK + l) * CHUNK;
    for (int sb = 0; sb < 4; ++sb) {
#pragma unroll
        for (int i = 0; i < 16; ++i) {
            int e = threadIdx.x + i * 256;
            int r = e >> 6, pcol = e & 63;
            xdt_sh[r][pcol] = bf2f(xc[(base_s + sb * 64 + r) * CONV_DIM + h * HEAD_DIM + pcol]) * dt_sh[sb * 64 + r];
        }
        __syncthreads();
        if (l >= sb * 64) {
            int send = min(63, l - sb * 64);
            for (int sp = 0; sp <= send; ++sp) {
                int s = sb * 64 + sp;
                float coeff = Grow[s] * __expf(myA - dA_sh[s]);
#pragma unroll
                for (int p = 0; p < 64; ++p) acc[p] += coeff * xdt_sh[sp][p];
            }
        }
        __syncthreads();
    }
    float Dh = Dp[h];
    const unsigned short* xrow = xc + (base_s + l) * CONV_DIM + h * HEAD_DIM;
    unsigned short* yrow = y + (base_s + l) * (long)HID + h * HEAD_DIM;
#pragma unroll
    for (int p = 0; p < 64; ++p) yrow[p] = f2bf(acc[p] + Dh * bf2f(xrow[p]));
}

// ---------------- gate with silu(z), RMSNorm, bf16 out ----------------
__global__ __launch_bounds__(256) void k_norm(
    const unsigned short* __restrict__ y, const unsigned short* __restrict__ z,
    const float* __restrict__ norm_w, unsigned short* __restrict__ yb)
{
    int s = blockIdx.x;
    int t = threadIdx.x;
    const unsigned short* yrow = y + (long)s * HID;
    const unsigned short* zrow = z + (long)s * HID;
    float vals[16];
    float ss = 0.f;
#pragma unroll
    for (int i = 0; i < 16; ++i) {
        int j = t + i * 256;
        float yv = bf2f(yrow[j]);
        float zv = bf2f(zrow[j]);
        float g = yv * (zv / (1.f + __expf(-zv)));
        vals[i] = g;
        ss += g * g;
    }
#pragma unroll
    for (int off = 32; off > 0; off >>= 1) ss += __shfl_down(ss, off);
    __shared__ float wsum[4];
    int lane = t & 63, wid = t >> 6;
    if (lane == 0) wsum[wid] = ss;
    __syncthreads();
    float total = wsum[0] + wsum[1] + wsum[2] + wsum[3];
    float scale = rsqrtf(total / HID + 1e-5f);
#pragma unroll
    for (int i = 0; i < 16; ++i) {
        int j = t + i * 256;
        yb[(long)s * HID + j] = f2bf(vals[i] * scale * norm_w[j]);
    }
}

// ---------------- launch ----------------
extern "C" void kernel_launch(void* const* d_in, const int* in_sizes, int n_in,
                              void* d_out, int out_size, void* d_ws, size_t ws_size,
                              hipStream_t stream) {
    const float* x          = (const float*)d_in[0];
    const float* in_proj_w  = (const float*)d_in[1];
    const float* conv_w     = (const float*)d_in[2];
    const float* dt_bias    = (const float*)d_in[3];
    const float* A_log      = (const float*)d_in[4];
    const float* Dp         = (const float*)d_in[5];
    const float* norm_w     = (const float*)d_in[6];
    const float* out_proj_w = (const float*)d_in[7];
    char* ws = (char*)d_ws;

    // workspace layout (bytes) — total 131,600,384
    const size_t off_xb    = 0;
    const size_t off_wbin  = off_xb    + (size_t)SEQ * DIMIN * 2;
    const size_t off_xbcd  = off_wbin  + (size_t)WROWS * DIMIN * 2;
    const size_t off_xc    = off_xbcd  + (size_t)SEQ * XBCD_N * 2;
    const size_t off_dtraw = off_xc    + (size_t)SEQ * CONV_DIM * 2;
    const size_t off_dtv   = off_dtraw + (size_t)SEQ * 64 * 4;
    const size_t off_dAc   = off_dtv   + (size_t)SEQ * HEADS * 4;
    const size_t off_dAl   = off_dAc   + (size_t)SEQ * HEADS * 4;
    const size_t off_G     = off_dAl   + (size_t)NCHUNK * HEADS * 4;
    const size_t needed    = off_G     + (size_t)NCHUNK * CHUNK * CHUNK * 4;
    if (ws_size < needed) return;

    unsigned short* xb    = (unsigned short*)(ws + off_xb);
    unsigned short* wbin  = (unsigned short*)(ws + off_wbin);
    unsigned short* xbcd  = (unsigned short*)(ws + off_xbcd);
    unsigned short* xc    = (unsigned short*)(ws + off_xc);
    float* dtraw = (float*)(ws + off_dtraw);
    float* dtv   = (float*)(ws + off_dtv);
    float* dAc   = (float*)(ws + off_dAc);
    float* dAl   = (float*)(ws + off_dAl);
    float* G     = (float*)(ws + off_G);

    float* states      = (float*)d_out;
    unsigned short* z  = (unsigned short*)d_out;
    unsigned short* y  = xbcd;
    unsigned short* yb = xc;
    unsigned short* wob = wbin;

    { long n = (long)SEQ * DIMIN;
      k_convert<<<(unsigned)((n + 255) / 256), 256, 0, stream>>>(x, xb, n, n); }
    { long n = (long)WROWS * DIMIN, nsrc = (long)D_IN * DIMIN;
      k_convert<<<(unsigned)((n + 255) / 256), 256, 0, stream>>>(in_proj_w, wbin, n, nsrc); }
    k_gemm<1><<<dim3(XBCD_N / BN, SEQ / BM), 256, 0, stream>>>(
        xb, wbin + (size_t)HID * DIMIN, (void*)xbcd, DIMIN, XBCD_N, dtraw, 4352);
    { long n = (long)SEQ * CONV_DIM;
      k_conv<<<(unsigned)((n + 255) / 256), 256, 0, stream>>>(xbcd, conv_w, xc); }
    k_dt<<<dim3(NCHUNK, HEADS), 256, 0, stream>>>(dtraw, dt_bias, A_log, dtv, dAc, dAl);
    k_G<<<dim3(NCHUNK, CHUNK), 256, 0, stream>>>(xc, G);
    k_states<<<dim3(NCHUNK, HEADS), 256, 0, stream>>>(xc, dtv, dAc, dAl, states);
    k_scan<<<(HEADS * HEAD_DIM * STATE) / 256, 256, 0, stream>>>(states, dAl);
    k_ssd_y<<<dim3(NCHUNK, HEADS), 256, 0, stream>>>(xc, G, dtv, dAc, states, Dp, y);
    k_gemm<1><<<dim3(HID / BN, SEQ / BM), 256, 0, stream>>>(
        xb, wbin, (void*)z, DIMIN, HID, nullptr, 0);
    k_norm<<<SEQ, 256, 0, stream>>>(y, z, norm_w, yb);
    { long n = (long)DIMIN * HID;
      k_convert<<<(unsigned)((n + 255) / 256), 256, 0, stream>>>(out_proj_w, wob, n, n); }
    k_gemm<0><<<dim3(DIMIN / BN, SEQ / BM), 256, 0, stream>>>(
        yb, wob, d_out, HID, DIMIN, nullptr, 0);
}

// Round 4
// 783.521 us; speedup vs baseline: 1.5597x; 1.2616x over previous
//
#include <hip/hip_runtime.h>
#include <cstdint>
#include <cstddef>

#define SEQ      4096
#define DIMIN    2048
#define HID      4096
#define STATE    128
#define HEADS    64
#define HEAD_DIM 64
#define CONV_DIM 4352   // HID + 2*STATE
#define D_IN     8512
#define WROWS    8576   // in_proj rows padded to 67*128
#define XBCD_N   4480   // xBC+dt GEMM cols: 4416 padded to 35*128
#define CHUNK    256
#define NCHUNK   16

typedef __attribute__((ext_vector_type(8))) short short8;
typedef __attribute__((ext_vector_type(4))) float floatx4;
typedef __attribute__((ext_vector_type(4))) unsigned int uintx4;

__device__ __forceinline__ unsigned short f2bf(float f) {
    union { float f; unsigned int u; } v; v.f = f;
    unsigned int r = v.u + 0x7FFFu + ((v.u >> 16) & 1u);
    return (unsigned short)(r >> 16);
}
__device__ __forceinline__ float bf2f(unsigned short u) {
    union { unsigned int u; float f; } v; v.u = ((unsigned int)u) << 16;
    return v.f;
}

// ---------------- fp32 -> bf16 convert (with zero tail padding) ----------------
__global__ void k_convert(const float* __restrict__ src, unsigned short* __restrict__ dst,
                          long n, long nsrc) {
    long i = (long)blockIdx.x * blockDim.x + threadIdx.x;
    if (i >= n) return;
    float v = (i < nsrc) ? src[i] : 0.f;
    dst[i] = f2bf(v);
}

// ---------------- bf16 MFMA GEMM: C[M,N] = A[M,K] * B[N,K]^T ----------------
#define BM 128
#define BN 128
#define BK 64
#define LDT 72   // padded LDS row stride (ushorts)

template <int BF16OUT>
__global__ __launch_bounds__(256) void k_gemm(
    const unsigned short* __restrict__ A, const unsigned short* __restrict__ B,
    void* __restrict__ Cout, int K, int ldc, float* __restrict__ aux, int auxc0)
{
    __shared__ __attribute__((aligned(16))) unsigned short As[BM * LDT];
    __shared__ __attribute__((aligned(16))) unsigned short Bs[BN * LDT];
    const int tid = threadIdx.x;
    const int bm = blockIdx.y, bn = blockIdx.x;
    const int wid = tid >> 6, lane = tid & 63;
    const int wm = (wid >> 1) * 64, wn = (wid & 1) * 64;
    const int lrow = lane & 15;
    const int lk = (lane >> 4) * 8;

    floatx4 acc[4][4];
#pragma unroll
    for (int i = 0; i < 4; ++i)
#pragma unroll
        for (int j = 0; j < 4; ++j) acc[i][j] = (floatx4){0.f, 0.f, 0.f, 0.f};

    const long a_base = (long)bm * BM * K;
    const long b_base = (long)bn * BN * K;

    for (int k0 = 0; k0 < K; k0 += BK) {
#pragma unroll
        for (int i = 0; i < 4; ++i) {
            int c = tid + i * 256;
            int row = c >> 3;
            int col = (c & 7) * 8;
            *(uintx4*)&As[row * LDT + col] = *(const uintx4*)&A[a_base + (long)row * K + k0 + col];
            *(uintx4*)&Bs[row * LDT + col] = *(const uintx4*)&B[b_base + (long)row * K + k0 + col];
        }
        __syncthreads();
#pragma unroll
        for (int kk = 0; kk < BK; kk += 32) {
            short8 af[4], bfr[4];
#pragma unroll
            for (int i = 0; i < 4; ++i)
                af[i] = *(const short8*)&As[(wm + i * 16 + lrow) * LDT + kk + lk];
#pragma unroll
            for (int j = 0; j < 4; ++j)
                bfr[j] = *(const short8*)&Bs[(wn + j * 16 + lrow) * LDT + kk + lk];
#pragma unroll
            for (int i = 0; i < 4; ++i)
#pragma unroll
                for (int j = 0; j < 4; ++j)
                    acc[i][j] = __builtin_amdgcn_mfma_f32_16x16x32_bf16(af[i], bfr[j], acc[i][j], 0, 0, 0);
        }
        __syncthreads();
    }
    const int rcol = lane & 15;
    const int rrow = (lane >> 4) * 4;
#pragma unroll
    for (int i = 0; i < 4; ++i)
#pragma unroll
        for (int j = 0; j < 4; ++j) {
            int col = bn * BN + wn + j * 16 + rcol;
#pragma unroll
            for (int r = 0; r < 4; ++r) {
                int row = bm * BM + wm + i * 16 + rrow + r;
                float v = acc[i][j][r];
                if (BF16OUT) {
                    ((unsigned short*)Cout)[(long)row * ldc + col] = f2bf(v);
                    if (aux && col >= auxc0 && col < auxc0 + 64)
                        aux[(long)row * 64 + (col - auxc0)] = v;
                } else {
                    ((float*)Cout)[(long)row * ldc + col] = v;
                }
            }
        }
}

// ---------------- causal conv1d (k=4) + SiLU, bf16 in/out ----------------
__global__ void k_conv(const unsigned short* __restrict__ xbcd, const float* __restrict__ convw,
                       unsigned short* __restrict__ xc) {
    long i = (long)blockIdx.x * 256 + threadIdx.x;
    if (i >= (long)SEQ * CONV_DIM) return;
    int c = (int)(i % CONV_DIM);
    int s = (int)(i / CONV_DIM);
    float w0 = convw[c * 4 + 0], w1 = convw[c * 4 + 1];
    float w2 = convw[c * 4 + 2], w3 = convw[c * 4 + 3];
    float acc = bf2f(xbcd[(long)s * XBCD_N + c]) * w3;
    if (s >= 1) acc += bf2f(xbcd[(long)(s - 1) * XBCD_N + c]) * w2;
    if (s >= 2) acc += bf2f(xbcd[(long)(s - 2) * XBCD_N + c]) * w1;
    if (s >= 3) acc += bf2f(xbcd[(long)(s - 3) * XBCD_N + c]) * w0;
    float sl = acc / (1.f + __expf(-acc));
    xc[i] = f2bf(sl);
}

// ---------------- dt = softplus(dtraw+bias), dA = dt*A, per-chunk inclusive cumsum ----------------
__global__ __launch_bounds__(256) void k_dt(const float* __restrict__ dtraw,
        const float* __restrict__ dt_bias, const float* __restrict__ A_log,
        float* __restrict__ dtv, float* __restrict__ dAc, float* __restrict__ dAlast)
{
    int c = blockIdx.x, h = blockIdx.y;
    int l = threadIdx.x;
    __shared__ float sh[CHUNK];
    float v = dtraw[(long)(c * CHUNK + l) * 64 + h] + dt_bias[h];
    float dt = (v > 20.f) ? v : log1pf(__expf(v));
    float Ah = -__expf(A_log[h]);
    float dA = dt * Ah;
    sh[l] = dA;
    __syncthreads();
    float x = dA;
#pragma unroll
    for (int off = 1; off < CHUNK; off <<= 1) {
        float t = (l >= off) ? sh[l - off] : 0.f;
        __syncthreads();
        x += t;
        sh[l] = x;
        __syncthreads();
    }
    dtv[(long)(c * CHUNK + l) * HEADS + h] = dt;
    dAc[(long)(c * CHUNK + l) * HEADS + h] = x;
    if (l == CHUNK - 1) dAlast[c * HEADS + h] = x;
}

// ---------------- G[c][l][s] = C[l] . B[s] ----------------
__global__ __launch_bounds__(256) void k_G(const unsigned short* __restrict__ xc, float* __restrict__ G) {
    int c = blockIdx.x, l = blockIdx.y;
    int s = threadIdx.x;
    __shared__ float Csh[STATE];
    if (s < STATE) Csh[s] = bf2f(xc[(long)(c * CHUNK + l) * CONV_DIM + HID + STATE + s]);
    __syncthreads();
    const unsigned short* Brow = xc + (long)(c * CHUNK + s) * CONV_DIM + HID;
    float acc = 0.f;
#pragma unroll
    for (int n = 0; n < STATE; n += 8) {
        short8 b8 = *(const short8*)&Brow[n];
#pragma unroll
        for (int j = 0; j < 8; ++j)
            acc += Csh[n + j] * bf2f((unsigned short)b8[j]);
    }
    G[((long)c * CHUNK + l) * CHUNK + s] = acc;
}

// ---------------- states[c,h,p,n] = sum_l B[l,n]*exp(dAlast-dAc[l])*dt[l]*xh[l,p] ----------------
__global__ __launch_bounds__(256) void k_states(
    const unsigned short* __restrict__ xc, const float* __restrict__ dtv,
    const float* __restrict__ dAc, const float* __restrict__ dAlast,
    float* __restrict__ states)
{
    int c = blockIdx.x, h = blockIdx.y;
    int t = threadIdx.x;
    __shared__ float xs[64][64];
    __shared__ float dA_sh[CHUNK], dt_sh[CHUNK];
    long base_s = (long)c * CHUNK;
    dA_sh[t] = dAc[(base_s + t) * HEADS + h];
    dt_sh[t] = dtv[(base_s + t) * HEADS + h];
    __syncthreads();
    float dAl = dAlast[c * HEADS + h];
    int p0 = t >> 5;
    int n0 = t & 31;
    float acc[8][4];
#pragma unroll
    for (int ip = 0; ip < 8; ++ip)
#pragma unroll
        for (int j = 0; j < 4; ++j) acc[ip][j] = 0.f;

    for (int lb = 0; lb < 4; ++lb) {
#pragma unroll
        for (int i = 0; i < 16; ++i) {
            int e = t + i * 256;
            int r = e >> 6, pcol = e & 63;
            float ds = __expf(dAl - dA_sh[lb * 64 + r]) * dt_sh[lb * 64 + r];
            xs[r][pcol] = bf2f(xc[(base_s + lb * 64 + r) * CONV_DIM + h * HEAD_DIM + pcol]) * ds;
        }
        __syncthreads();
        for (int lp = 0; lp < 64; ++lp) {
            const unsigned short* Brow = xc + (base_s + lb * 64 + lp) * CONV_DIM + HID;
            float bv[4];
#pragma unroll
            for (int j = 0; j < 4; ++j) bv[j] = bf2f(Brow[n0 + 32 * j]);
#pragma unroll
            for (int ip = 0; ip < 8; ++ip) {
                float xv = xs[lp][p0 + 8 * ip];
#pragma unroll
                for (int j = 0; j < 4; ++j) acc[ip][j] += xv * bv[j];
            }
        }
        __syncthreads();
    }
    float* Sb = states + (long)(c * HEADS + h) * HEAD_DIM * STATE;
#pragma unroll
    for (int ip = 0; ip < 8; ++ip)
#pragma unroll
        for (int j = 0; j < 4; ++j)
            Sb[(p0 + 8 * ip) * STATE + n0 + 32 * j] = acc[ip][j];
}

// ---------------- sequential chunk-state scan (in place: states[c] := prev state) ----------------
__global__ void k_scan(float* __restrict__ states, const float* __restrict__ dAlast) {
    int t = blockIdx.x * 256 + threadIdx.x;
    if (t >= HEADS * HEAD_DIM * STATE) return;
    int h = t >> 13;
    const long stride = (long)HEADS * HEAD_DIM * STATE;
    float carry = 0.f;
    for (int c = 0; c < NCHUNK; ++c) {
        float s = states[c * stride + t];
        float dec = __expf(dAlast[c * HEADS + h]);
        states[c * stride + t] = carry;
        carry = carry * dec + s;
    }
}

// ---------------- y = y_off + y_diag + D*x (MFMA version), bf16 out ----------------
// Per block (c,h): y[256 l][64 p] = M[256,256] @ xdt[256,64] + Ce[256,128] @ prevT[128,64].
// Fragment convention identical to k_gemm: both operands [out][k], lane&15=out,
// (lane>>4)*8=k-group; C/D col=lane&15 (p), row=(lane>>4)*4+r (l).
// M built in registers (G load + exp); xdt staged transposed [p][s] bf16 in LDS;
// prev staged [p][n] bf16 in LDS. Wave w owns rows [64w,64w+64), skips s-tiles
// above the diagonal. 2 barriers total (round-3 had 10, VALUBusy 44%, 301 us).
#define XDTS 264   // row stride: 528 B -> 16B-aligned rows, 4-bank advance (2-way, free)
#define PVS  136   // row stride: 272 B -> same property
__global__ __launch_bounds__(256, 3) void k_ssd_y(
    const unsigned short* __restrict__ xc, const float* __restrict__ G,
    const float* __restrict__ dtv, const float* __restrict__ dAc,
    const float* __restrict__ prev, const float* __restrict__ Dp,
    unsigned short* __restrict__ y)
{
    __shared__ __attribute__((aligned(16))) unsigned short xdtT[64 * XDTS];
    __shared__ __attribute__((aligned(16))) unsigned short pvB[64 * PVS];
    __shared__ float dA_sh[CHUNK];
    __shared__ float dt_sh[CHUNK];
    const int c = blockIdx.x, h = blockIdx.y;
    const int t = threadIdx.x;
    const int w = t >> 6, lane = t & 63;
    const long base_s = (long)c * CHUNK;

    dA_sh[t] = dAc[(base_s + t) * HEADS + h];
    dt_sh[t] = dtv[(base_s + t) * HEADS + h];
    __syncthreads();

    // stage prev[p][n] -> bf16 LDS
    {
        const float* Pb = prev + (long)(c * HEADS + h) * HEAD_DIM * STATE;
#pragma unroll
        for (int i = 0; i < 32; ++i) {
            int e = t + i * 256;
            int p = e >> 7, n = e & 127;
            pvB[p * PVS + n] = f2bf(Pb[e]);
        }
    }
    // stage xdtT[p][s] = bf16(x[s][p]*dt[s])  (coalesced global reads; strided b16
    // LDS writes ~8-way, once per block — acceptable)
#pragma unroll
    for (int i = 0; i < 64; ++i) {
        int e = t + i * 256;
        int p = e & 63, s = e >> 6;
        float v = bf2f(xc[(base_s + s) * CONV_DIM + h * HEAD_DIM + p]) * dt_sh[s];
        xdtT[p * XDTS + s] = f2bf(v);
    }
    __syncthreads();

    floatx4 acc[4][4];
#pragma unroll
    for (int i = 0; i < 4; ++i)
#pragma unroll
        for (int j = 0; j < 4; ++j) acc[i][j] = (floatx4){0.f, 0.f, 0.f, 0.f};

    const int lrow = lane & 15;
    const int kgrp = (lane >> 4) * 8;
    float myA[4], eAl[4];
#pragma unroll
    for (int i = 0; i < 4; ++i) {
        int l = w * 64 + i * 16 + lrow;
        myA[i] = dA_sh[l];
        eAl[i] = __expf(myA[i]);
    }

    // ---- off term: k = n over STATE ----
    for (int k0 = 0; k0 < STATE; k0 += 32) {
        short8 af[4], bfr[4];
#pragma unroll
        for (int i = 0; i < 4; ++i) {
            int l = w * 64 + i * 16 + lrow;
            union { short8 v; unsigned short u[8]; } r, o;
            r.v = *(const short8*)&xc[(base_s + l) * CONV_DIM + (HID + STATE) + k0 + kgrp];
#pragma unroll
            for (int j = 0; j < 8; ++j) o.u[j] = f2bf(bf2f(r.u[j]) * eAl[i]);
            af[i] = o.v;
        }
#pragma unroll
        for (int j = 0; j < 4; ++j)
            bfr[j] = *(const short8*)&pvB[(j * 16 + lrow) * PVS + k0 + kgrp];
#pragma unroll
        for (int i = 0; i < 4; ++i)
#pragma unroll
            for (int j = 0; j < 4; ++j)
                acc[i][j] = __builtin_amdgcn_mfma_f32_16x16x32_bf16(af[i], bfr[j], acc[i][j], 0, 0, 0);
    }

    // ---- diag term: k = s, only tiles not fully above the diagonal ----
    for (int k0 = 0; k0 < (w + 1) * 64; k0 += 32) {
        short8 af[4], bfr[4];
#pragma unroll
        for (int i = 0; i < 4; ++i) {
            int l = w * 64 + i * 16 + lrow;
            const float* Gp = G + (base_s + l) * (long)CHUNK + k0 + kgrp;
            float4 g0 = *(const float4*)Gp;
            float4 g1 = *(const float4*)(Gp + 4);
            float ga[8] = {g0.x, g0.y, g0.z, g0.w, g1.x, g1.y, g1.z, g1.w};
            union { short8 v; unsigned short u[8]; } o;
#pragma unroll
            for (int j = 0; j < 8; ++j) {
                int s = k0 + kgrp + j;
                float e = __expf(fminf(myA[i] - dA_sh[s], 0.f));
                float m = (s <= l) ? ga[j] * e : 0.f;
                o.u[j] = f2bf(m);
            }
            af[i] = o.v;
        }
#pragma unroll
        for (int j = 0; j < 4; ++j)
            bfr[j] = *(const short8*)&xdtT[(j * 16 + lrow) * XDTS + k0 + kgrp];
#pragma unroll
        for (int i = 0; i < 4; ++i)
#pragma unroll
            for (int j = 0; j < 4; ++j)
                acc[i][j] = __builtin_amdgcn_mfma_f32_16x16x32_bf16(af[i], bfr[j], acc[i][j], 0, 0, 0);
    }

    // ---- epilogue: + D*x, bf16 store ----
    const float Dh = Dp[h];
    const int rrow = (lane >> 4) * 4;
#pragma unroll
    for (int i = 0; i < 4; ++i)
#pragma unroll
        for (int j = 0; j < 4; ++j) {
            int p = j * 16 + lrow;
#pragma unroll
            for (int r = 0; r < 4; ++r) {
                int l = w * 64 + i * 16 + rrow + r;
                float v = acc[i][j][r] + Dh * bf2f(xc[(base_s + l) * CONV_DIM + h * HEAD_DIM + p]);
                y[(base_s + l) * (long)HID + h * HEAD_DIM + p] = f2bf(v);
            }
        }
}

// ---------------- gate with silu(z), RMSNorm, bf16 out ----------------
__global__ __launch_bounds__(256) void k_norm(
    const unsigned short* __restrict__ y, const unsigned short* __restrict__ z,
    const float* __restrict__ norm_w, unsigned short* __restrict__ yb)
{
    int s = blockIdx.x;
    int t = threadIdx.x;
    const unsigned short* yrow = y + (long)s * HID;
    const unsigned short* zrow = z + (long)s * HID;
    float vals[16];
    float ss = 0.f;
#pragma unroll
    for (int i = 0; i < 16; ++i) {
        int j = t + i * 256;
        float yv = bf2f(yrow[j]);
        float zv = bf2f(zrow[j]);
        float g = yv * (zv / (1.f + __expf(-zv)));
        vals[i] = g;
        ss += g * g;
    }
#pragma unroll
    for (int off = 32; off > 0; off >>= 1) ss += __shfl_down(ss, off);
    __shared__ float wsum[4];
    int lane = t & 63, wid = t >> 6;
    if (lane == 0) wsum[wid] = ss;
    __syncthreads();
    float total = wsum[0] + wsum[1] + wsum[2] + wsum[3];
    float scale = rsqrtf(total / HID + 1e-5f);
#pragma unroll
    for (int i = 0; i < 16; ++i) {
        int j = t + i * 256;
        yb[(long)s * HID + j] = f2bf(vals[i] * scale * norm_w[j]);
    }
}

// ---------------- launch ----------------
extern "C" void kernel_launch(void* const* d_in, const int* in_sizes, int n_in,
                              void* d_out, int out_size, void* d_ws, size_t ws_size,
                              hipStream_t stream) {
    const float* x          = (const float*)d_in[0];
    const float* in_proj_w  = (const float*)d_in[1];
    const float* conv_w     = (const float*)d_in[2];
    const float* dt_bias    = (const float*)d_in[3];
    const float* A_log      = (const float*)d_in[4];
    const float* Dp         = (const float*)d_in[5];
    const float* norm_w     = (const float*)d_in[6];
    const float* out_proj_w = (const float*)d_in[7];
    char* ws = (char*)d_ws;

    // workspace layout (bytes) — total 131,600,384
    const size_t off_xb    = 0;
    const size_t off_wbin  = off_xb    + (size_t)SEQ * DIMIN * 2;
    const size_t off_xbcd  = off_wbin  + (size_t)WROWS * DIMIN * 2;
    const size_t off_xc    = off_xbcd  + (size_t)SEQ * XBCD_N * 2;
    const size_t off_dtraw = off_xc    + (size_t)SEQ * CONV_DIM * 2;
    const size_t off_dtv   = off_dtraw + (size_t)SEQ * 64 * 4;
    const size_t off_dAc   = off_dtv   + (size_t)SEQ * HEADS * 4;
    const size_t off_dAl   = off_dAc   + (size_t)SEQ * HEADS * 4;
    const size_t off_G     = off_dAl   + (size_t)NCHUNK * HEADS * 4;
    const size_t needed    = off_G     + (size_t)NCHUNK * CHUNK * CHUNK * 4;
    if (ws_size < needed) return;

    unsigned short* xb    = (unsigned short*)(ws + off_xb);
    unsigned short* wbin  = (unsigned short*)(ws + off_wbin);
    unsigned short* xbcd  = (unsigned short*)(ws + off_xbcd);
    unsigned short* xc    = (unsigned short*)(ws + off_xc);
    float* dtraw = (float*)(ws + off_dtraw);
    float* dtv   = (float*)(ws + off_dtv);
    float* dAc   = (float*)(ws + off_dAc);
    float* dAl   = (float*)(ws + off_dAl);
    float* G     = (float*)(ws + off_G);

    float* states      = (float*)d_out;
    unsigned short* z  = (unsigned short*)d_out;
    unsigned short* y  = xbcd;
    unsigned short* yb = xc;
    unsigned short* wob = wbin;

    { long n = (long)SEQ * DIMIN;
      k_convert<<<(unsigned)((n + 255) / 256), 256, 0, stream>>>(x, xb, n, n); }
    { long n = (long)WROWS * DIMIN, nsrc = (long)D_IN * DIMIN;
      k_convert<<<(unsigned)((n + 255) / 256), 256, 0, stream>>>(in_proj_w, wbin, n, nsrc); }
    k_gemm<1><<<dim3(XBCD_N / BN, SEQ / BM), 256, 0, stream>>>(
        xb, wbin + (size_t)HID * DIMIN, (void*)xbcd, DIMIN, XBCD_N, dtraw, 4352);
    { long n = (long)SEQ * CONV_DIM;
      k_conv<<<(unsigned)((n + 255) / 256), 256, 0, stream>>>(xbcd, conv_w, xc); }
    k_dt<<<dim3(NCHUNK, HEADS), 256, 0, stream>>>(dtraw, dt_bias, A_log, dtv, dAc, dAl);
    k_G<<<dim3(NCHUNK, CHUNK), 256, 0, stream>>>(xc, G);
    k_states<<<dim3(NCHUNK, HEADS), 256, 0, stream>>>(xc, dtv, dAc, dAl, states);
    k_scan<<<(HEADS * HEAD_DIM * STATE) / 256, 256, 0, stream>>>(states, dAl);
    k_ssd_y<<<dim3(NCHUNK, HEADS), 256, 0, stream>>>(xc, G, dtv, dAc, states, Dp, y);
    k_gemm<1><<<dim3(HID / BN, SEQ / BM), 256, 0, stream>>>(
        xb, wbin, (void*)z, DIMIN, HID, nullptr, 0);
    k_norm<<<SEQ, 256, 0, stream>>>(y, z, norm_w, yb);
    { long n = (long)DIMIN * HID;
      k_convert<<<(unsigned)((n + 255) / 256), 256, 0, stream>>>(out_proj_w, wob, n, n); }
    k_gemm<0><<<dim3(DIMIN / BN, SEQ / BM), 256, 0, stream>>>(
        yb, wob, d_out, HID, DIMIN, nullptr, 0);
}

// Round 5
// 762.192 us; speedup vs baseline: 1.6033x; 1.0280x over previous
//
#include <hip/hip_runtime.h>
#include <cstdint>
#include <cstddef>

#define SEQ      4096
#define DIMIN    2048
#define HID      4096
#define STATE    128
#define HEADS    64
#define HEAD_DIM 64
#define CONV_DIM 4352   // HID + 2*STATE
#define D_IN     8512
#define WROWS    8576   // in_proj rows padded to 67*128
#define XBCD_N   4480   // xBC+dt GEMM cols: 4416 padded to 35*128
#define CHUNK    256
#define NCHUNK   16

typedef __attribute__((ext_vector_type(8))) short short8;
typedef __attribute__((ext_vector_type(4))) float floatx4;
typedef __attribute__((ext_vector_type(4))) unsigned int uintx4;

#define AS1 __attribute__((address_space(1)))
#define AS3 __attribute__((address_space(3)))
__device__ __forceinline__ void gload_lds16(const void* g, void* l) {
    __builtin_amdgcn_global_load_lds((const AS1 unsigned int*)g, (AS3 unsigned int*)l, 16, 0, 0);
}

__device__ __forceinline__ unsigned short f2bf(float f) {
    union { float f; unsigned int u; } v; v.f = f;
    unsigned int r = v.u + 0x7FFFu + ((v.u >> 16) & 1u);
    return (unsigned short)(r >> 16);
}
__device__ __forceinline__ float bf2f(unsigned short u) {
    union { unsigned int u; float f; } v; v.u = ((unsigned int)u) << 16;
    return v.f;
}

// ---------------- fp32 -> bf16 convert (with zero tail padding) ----------------
__global__ void k_convert(const float* __restrict__ src, unsigned short* __restrict__ dst,
                          long n, long nsrc) {
    long i = (long)blockIdx.x * blockDim.x + threadIdx.x;
    if (i >= n) return;
    float v = (i < nsrc) ? src[i] : 0.f;
    dst[i] = f2bf(v);
}

// ---------------- bf16 MFMA GEMM: C[M,N] = A[M,K] * B[N,K]^T ----------------
// m97-ladder step 3: global_load_lds width=16 staging + XOR-swizzled unpadded LDS
// (slot s of row r holds global k-group s^(r&7)) + 8-wide column super-groups for
// L2 locality. Round-4 version (VGPR staging, LDT=72): 553 TF, 9.2M bank conflicts.
#define BM 128
#define BN 128
#define BK 64

template <int BF16OUT>
__global__ __launch_bounds__(256) void k_gemm(
    const unsigned short* __restrict__ A, const unsigned short* __restrict__ B,
    void* __restrict__ Cout, int K, int ldc, float* __restrict__ aux, int auxc0)
{
    __shared__ __attribute__((aligned(16))) unsigned short As[BM * BK];
    __shared__ __attribute__((aligned(16))) unsigned short Bs[BN * BK];
    const int tid = threadIdx.x;

    // L2 super-grouping: groups of GN column-tiles x all row-tiles
    const int GN = 8;
    const int nbx = gridDim.x, nby = gridDim.y;
    int flat = blockIdx.y * nbx + blockIdx.x;
    int group = flat / (GN * nby);
    int gw = min(GN, nbx - group * GN);
    int rem = flat - group * (GN * nby);
    int bn = group * GN + rem % gw;
    int bm = rem / gw;

    const int wid = tid >> 6, lane = tid & 63;
    const int wm = (wid >> 1) * 64, wn = (wid & 1) * 64;
    const int lrow = lane & 15;
    const int gk = lane >> 4;                     // k-group 0..3 within fragment
    const int srow = lane >> 3;                   // staging: row within 8-row span
    const int sgrp = (lane & 7) ^ (lane >> 3);    // staging: swizzled global col-group

    floatx4 acc[4][4];
#pragma unroll
    for (int i = 0; i < 4; ++i)
#pragma unroll
        for (int j = 0; j < 4; ++j) acc[i][j] = (floatx4){0.f, 0.f, 0.f, 0.f};

    const long a_base = (long)bm * BM * K;
    const long b_base = (long)bn * BN * K;

    for (int k0 = 0; k0 < K; k0 += BK) {
        const unsigned short* Ak = A + a_base + k0;
        const unsigned short* Bk = B + b_base + k0;
#pragma unroll
        for (int i = 0; i < 4; ++i) {
            int rbase = wid * 32 + i * 8;
            gload_lds16(Ak + (long)(rbase + srow) * K + sgrp * 8, &As[rbase * BK]);
            gload_lds16(Bk + (long)(rbase + srow) * K + sgrp * 8, &Bs[rbase * BK]);
        }
        __syncthreads();
#pragma unroll
        for (int kk = 0; kk < BK; kk += 32) {
            const int slot8 = (((kk >> 3) + gk) ^ (lrow & 7)) * 8;
            short8 af[4], bfr[4];
#pragma unroll
            for (int i = 0; i < 4; ++i)
                af[i] = *(const short8*)&As[(wm + i * 16 + lrow) * BK + slot8];
#pragma unroll
            for (int j = 0; j < 4; ++j)
                bfr[j] = *(const short8*)&Bs[(wn + j * 16 + lrow) * BK + slot8];
#pragma unroll
            for (int i = 0; i < 4; ++i)
#pragma unroll
                for (int j = 0; j < 4; ++j)
                    acc[i][j] = __builtin_amdgcn_mfma_f32_16x16x32_bf16(af[i], bfr[j], acc[i][j], 0, 0, 0);
        }
        __syncthreads();
    }
    const int rcol = lane & 15;
    const int rrow = (lane >> 4) * 4;
#pragma unroll
    for (int i = 0; i < 4; ++i)
#pragma unroll
        for (int j = 0; j < 4; ++j) {
            int col = bn * BN + wn + j * 16 + rcol;
#pragma unroll
            for (int r = 0; r < 4; ++r) {
                int row = bm * BM + wm + i * 16 + rrow + r;
                float v = acc[i][j][r];
                if (BF16OUT) {
                    ((unsigned short*)Cout)[(long)row * ldc + col] = f2bf(v);
                    if (aux && col >= auxc0 && col < auxc0 + 64)
                        aux[(long)row * 64 + (col - auxc0)] = v;
                } else {
                    ((float*)Cout)[(long)row * ldc + col] = v;
                }
            }
        }
}

// ---------------- causal conv1d (k=4) + SiLU, bf16 in/out ----------------
__global__ void k_conv(const unsigned short* __restrict__ xbcd, const float* __restrict__ convw,
                       unsigned short* __restrict__ xc) {
    long i = (long)blockIdx.x * 256 + threadIdx.x;
    if (i >= (long)SEQ * CONV_DIM) return;
    int c = (int)(i % CONV_DIM);
    int s = (int)(i / CONV_DIM);
    float w0 = convw[c * 4 + 0], w1 = convw[c * 4 + 1];
    float w2 = convw[c * 4 + 2], w3 = convw[c * 4 + 3];
    float acc = bf2f(xbcd[(long)s * XBCD_N + c]) * w3;
    if (s >= 1) acc += bf2f(xbcd[(long)(s - 1) * XBCD_N + c]) * w2;
    if (s >= 2) acc += bf2f(xbcd[(long)(s - 2) * XBCD_N + c]) * w1;
    if (s >= 3) acc += bf2f(xbcd[(long)(s - 3) * XBCD_N + c]) * w0;
    float sl = acc / (1.f + __expf(-acc));
    xc[i] = f2bf(sl);
}

// ---------------- dt = softplus(dtraw+bias), dA = dt*A, per-chunk inclusive cumsum ----------------
__global__ __launch_bounds__(256) void k_dt(const float* __restrict__ dtraw,
        const float* __restrict__ dt_bias, const float* __restrict__ A_log,
        float* __restrict__ dtv, float* __restrict__ dAc, float* __restrict__ dAlast)
{
    int c = blockIdx.x, h = blockIdx.y;
    int l = threadIdx.x;
    __shared__ float sh[CHUNK];
    float v = dtraw[(long)(c * CHUNK + l) * 64 + h] + dt_bias[h];
    float dt = (v > 20.f) ? v : log1pf(__expf(v));
    float Ah = -__expf(A_log[h]);
    float dA = dt * Ah;
    sh[l] = dA;
    __syncthreads();
    float x = dA;
#pragma unroll
    for (int off = 1; off < CHUNK; off <<= 1) {
        float t = (l >= off) ? sh[l - off] : 0.f;
        __syncthreads();
        x += t;
        sh[l] = x;
        __syncthreads();
    }
    dtv[(long)(c * CHUNK + l) * HEADS + h] = dt;
    dAc[(long)(c * CHUNK + l) * HEADS + h] = x;
    if (l == CHUNK - 1) dAlast[c * HEADS + h] = x;
}

// ---------------- G[c][l][s] = C[l] . B[s] ----------------
__global__ __launch_bounds__(256) void k_G(const unsigned short* __restrict__ xc, float* __restrict__ G) {
    int c = blockIdx.x, l = blockIdx.y;
    int s = threadIdx.x;
    __shared__ float Csh[STATE];
    if (s < STATE) Csh[s] = bf2f(xc[(long)(c * CHUNK + l) * CONV_DIM + HID + STATE + s]);
    __syncthreads();
    const unsigned short* Brow = xc + (long)(c * CHUNK + s) * CONV_DIM + HID;
    float acc = 0.f;
#pragma unroll
    for (int n = 0; n < STATE; n += 8) {
        short8 b8 = *(const short8*)&Brow[n];
#pragma unroll
        for (int j = 0; j < 8; ++j)
            acc += Csh[n + j] * bf2f((unsigned short)b8[j]);
    }
    G[((long)c * CHUNK + l) * CHUNK + s] = acc;
}

// ---------------- states[c,h,p,n] = sum_l B[l,n]*exp(dAlast-dAc[l])*dt[l]*xh[l,p] ----------------
__global__ __launch_bounds__(256) void k_states(
    const unsigned short* __restrict__ xc, const float* __restrict__ dtv,
    const float* __restrict__ dAc, const float* __restrict__ dAlast,
    float* __restrict__ states)
{
    int c = blockIdx.x, h = blockIdx.y;
    int t = threadIdx.x;
    __shared__ float xs[64][64];
    __shared__ float dA_sh[CHUNK], dt_sh[CHUNK];
    long base_s = (long)c * CHUNK;
    dA_sh[t] = dAc[(base_s + t) * HEADS + h];
    dt_sh[t] = dtv[(base_s + t) * HEADS + h];
    __syncthreads();
    float dAl = dAlast[c * HEADS + h];
    int p0 = t >> 5;
    int n0 = t & 31;
    float acc[8][4];
#pragma unroll
    for (int ip = 0; ip < 8; ++ip)
#pragma unroll
        for (int j = 0; j < 4; ++j) acc[ip][j] = 0.f;

    for (int lb = 0; lb < 4; ++lb) {
#pragma unroll
        for (int i = 0; i < 16; ++i) {
            int e = t + i * 256;
            int r = e >> 6, pcol = e & 63;
            float ds = __expf(dAl - dA_sh[lb * 64 + r]) * dt_sh[lb * 64 + r];
            xs[r][pcol] = bf2f(xc[(base_s + lb * 64 + r) * CONV_DIM + h * HEAD_DIM + pcol]) * ds;
        }
        __syncthreads();
        for (int lp = 0; lp < 64; ++lp) {
            const unsigned short* Brow = xc + (base_s + lb * 64 + lp) * CONV_DIM + HID;
            float bv[4];
#pragma unroll
            for (int j = 0; j < 4; ++j) bv[j] = bf2f(Brow[n0 + 32 * j]);
#pragma unroll
            for (int ip = 0; ip < 8; ++ip) {
                float xv = xs[lp][p0 + 8 * ip];
#pragma unroll
                for (int j = 0; j < 4; ++j) acc[ip][j] += xv * bv[j];
            }
        }
        __syncthreads();
    }
    float* Sb = states + (long)(c * HEADS + h) * HEAD_DIM * STATE;
#pragma unroll
    for (int ip = 0; ip < 8; ++ip)
#pragma unroll
        for (int j = 0; j < 4; ++j)
            Sb[(p0 + 8 * ip) * STATE + n0 + 32 * j] = acc[ip][j];
}

// ---------------- sequential chunk-state scan (in place: states[c] := prev state) ----------------
__global__ void k_scan(float* __restrict__ states, const float* __restrict__ dAlast) {
    int t = blockIdx.x * 256 + threadIdx.x;
    if (t >= HEADS * HEAD_DIM * STATE) return;
    int h = t >> 13;
    const long stride = (long)HEADS * HEAD_DIM * STATE;
    float carry = 0.f;
    for (int c = 0; c < NCHUNK; ++c) {
        float s = states[c * stride + t];
        float dec = __expf(dAlast[c * HEADS + h]);
        states[c * stride + t] = carry;
        carry = carry * dec + s;
    }
}

// ---------------- y = y_off + y_diag + D*x (MFMA version), bf16 out ----------------
#define XDTS 264   // row stride: 528 B -> 16B-aligned rows, 4-bank advance (2-way, free)
#define PVS  136   // row stride: 272 B -> same property
__global__ __launch_bounds__(256, 3) void k_ssd_y(
    const unsigned short* __restrict__ xc, const float* __restrict__ G,
    const float* __restrict__ dtv, const float* __restrict__ dAc,
    const float* __restrict__ prev, const float* __restrict__ Dp,
    unsigned short* __restrict__ y)
{
    __shared__ __attribute__((aligned(16))) unsigned short xdtT[64 * XDTS];
    __shared__ __attribute__((aligned(16))) unsigned short pvB[64 * PVS];
    __shared__ float dA_sh[CHUNK];
    __shared__ float dt_sh[CHUNK];
    const int c = blockIdx.x, h = blockIdx.y;
    const int t = threadIdx.x;
    const int w = t >> 6, lane = t & 63;
    const long base_s = (long)c * CHUNK;

    dA_sh[t] = dAc[(base_s + t) * HEADS + h];
    dt_sh[t] = dtv[(base_s + t) * HEADS + h];
    __syncthreads();

    {
        const float* Pb = prev + (long)(c * HEADS + h) * HEAD_DIM * STATE;
#pragma unroll
        for (int i = 0; i < 32; ++i) {
            int e = t + i * 256;
            int p = e >> 7, n = e & 127;
            pvB[p * PVS + n] = f2bf(Pb[e]);
        }
    }
#pragma unroll
    for (int i = 0; i < 64; ++i) {
        int e = t + i * 256;
        int p = e & 63, s = e >> 6;
        float v = bf2f(xc[(base_s + s) * CONV_DIM + h * HEAD_DIM + p]) * dt_sh[s];
        xdtT[p * XDTS + s] = f2bf(v);
    }
    __syncthreads();

    floatx4 acc[4][4];
#pragma unroll
    for (int i = 0; i < 4; ++i)
#pragma unroll
        for (int j = 0; j < 4; ++j) acc[i][j] = (floatx4){0.f, 0.f, 0.f, 0.f};

    const int lrow = lane & 15;
    const int kgrp = (lane >> 4) * 8;
    float myA[4], eAl[4];
#pragma unroll
    for (int i = 0; i < 4; ++i) {
        int l = w * 64 + i * 16 + lrow;
        myA[i] = dA_sh[l];
        eAl[i] = __expf(myA[i]);
    }

    // ---- off term: k = n over STATE ----
    for (int k0 = 0; k0 < STATE; k0 += 32) {
        short8 af[4], bfr[4];
#pragma unroll
        for (int i = 0; i < 4; ++i) {
            int l = w * 64 + i * 16 + lrow;
            union { short8 v; unsigned short u[8]; } r, o;
            r.v = *(const short8*)&xc[(base_s + l) * CONV_DIM + (HID + STATE) + k0 + kgrp];
#pragma unroll
            for (int j = 0; j < 8; ++j) o.u[j] = f2bf(bf2f(r.u[j]) * eAl[i]);
            af[i] = o.v;
        }
#pragma unroll
        for (int j = 0; j < 4; ++j)
            bfr[j] = *(const short8*)&pvB[(j * 16 + lrow) * PVS + k0 + kgrp];
#pragma unroll
        for (int i = 0; i < 4; ++i)
#pragma unroll
            for (int j = 0; j < 4; ++j)
                acc[i][j] = __builtin_amdgcn_mfma_f32_16x16x32_bf16(af[i], bfr[j], acc[i][j], 0, 0, 0);
    }

    // ---- diag term: k = s, only tiles not fully above the diagonal ----
    for (int k0 = 0; k0 < (w + 1) * 64; k0 += 32) {
        short8 af[4], bfr[4];
#pragma unroll
        for (int i = 0; i < 4; ++i) {
            int l = w * 64 + i * 16 + lrow;
            const float* Gp = G + (base_s + l) * (long)CHUNK + k0 + kgrp;
            float4 g0 = *(const float4*)Gp;
            float4 g1 = *(const float4*)(Gp + 4);
            float ga[8] = {g0.x, g0.y, g0.z, g0.w, g1.x, g1.y, g1.z, g1.w};
            union { short8 v; unsigned short u[8]; } o;
#pragma unroll
            for (int j = 0; j < 8; ++j) {
                int s = k0 + kgrp + j;
                float e = __expf(fminf(myA[i] - dA_sh[s], 0.f));
                float m = (s <= l) ? ga[j] * e : 0.f;
                o.u[j] = f2bf(m);
            }
            af[i] = o.v;
        }
#pragma unroll
        for (int j = 0; j < 4; ++j)
            bfr[j] = *(const short8*)&xdtT[(j * 16 + lrow) * XDTS + k0 + kgrp];
#pragma unroll
        for (int i = 0; i < 4; ++i)
#pragma unroll
            for (int j = 0; j < 4; ++j)
                acc[i][j] = __builtin_amdgcn_mfma_f32_16x16x32_bf16(af[i], bfr[j], acc[i][j], 0, 0, 0);
    }

    // ---- epilogue: + D*x, bf16 store ----
    const float Dh = Dp[h];
    const int rrow = (lane >> 4) * 4;
#pragma unroll
    for (int i = 0; i < 4; ++i)
#pragma unroll
        for (int j = 0; j < 4; ++j) {
            int p = j * 16 + lrow;
#pragma unroll
            for (int r = 0; r < 4; ++r) {
                int l = w * 64 + i * 16 + rrow + r;
                float v = acc[i][j][r] + Dh * bf2f(xc[(base_s + l) * CONV_DIM + h * HEAD_DIM + p]);
                y[(base_s + l) * (long)HID + h * HEAD_DIM + p] = f2bf(v);
            }
        }
}

// ---------------- gate with silu(z), RMSNorm, bf16 out ----------------
__global__ __launch_bounds__(256) void k_norm(
    const unsigned short* __restrict__ y, const unsigned short* __restrict__ z,
    const float* __restrict__ norm_w, unsigned short* __restrict__ yb)
{
    int s = blockIdx.x;
    int t = threadIdx.x;
    const unsigned short* yrow = y + (long)s * HID;
    const unsigned short* zrow = z + (long)s * HID;
    float vals[16];
    float ss = 0.f;
#pragma unroll
    for (int i = 0; i < 16; ++i) {
        int j = t + i * 256;
        float yv = bf2f(yrow[j]);
        float zv = bf2f(zrow[j]);
        float g = yv * (zv / (1.f + __expf(-zv)));
        vals[i] = g;
        ss += g * g;
    }
#pragma unroll
    for (int off = 32; off > 0; off >>= 1) ss += __shfl_down(ss, off);
    __shared__ float wsum[4];
    int lane = t & 63, wid = t >> 6;
    if (lane == 0) wsum[wid] = ss;
    __syncthreads();
    float total = wsum[0] + wsum[1] + wsum[2] + wsum[3];
    float scale = rsqrtf(total / HID + 1e-5f);
#pragma unroll
    for (int i = 0; i < 16; ++i) {
        int j = t + i * 256;
        yb[(long)s * HID + j] = f2bf(vals[i] * scale * norm_w[j]);
    }
}

// ---------------- launch ----------------
extern "C" void kernel_launch(void* const* d_in, const int* in_sizes, int n_in,
                              void* d_out, int out_size, void* d_ws, size_t ws_size,
                              hipStream_t stream) {
    const float* x          = (const float*)d_in[0];
    const float* in_proj_w  = (const float*)d_in[1];
    const float* conv_w     = (const float*)d_in[2];
    const float* dt_bias    = (const float*)d_in[3];
    const float* A_log      = (const float*)d_in[4];
    const float* Dp         = (const float*)d_in[5];
    const float* norm_w     = (const float*)d_in[6];
    const float* out_proj_w = (const float*)d_in[7];
    char* ws = (char*)d_ws;

    // workspace layout (bytes) — total 131,600,384
    const size_t off_xb    = 0;
    const size_t off_wbin  = off_xb    + (size_t)SEQ * DIMIN * 2;
    const size_t off_xbcd  = off_wbin  + (size_t)WROWS * DIMIN * 2;
    const size_t off_xc    = off_xbcd  + (size_t)SEQ * XBCD_N * 2;
    const size_t off_dtraw = off_xc    + (size_t)SEQ * CONV_DIM * 2;
    const size_t off_dtv   = off_dtraw + (size_t)SEQ * 64 * 4;
    const size_t off_dAc   = off_dtv   + (size_t)SEQ * HEADS * 4;
    const size_t off_dAl   = off_dAc   + (size_t)SEQ * HEADS * 4;
    const size_t off_G     = off_dAl   + (size_t)NCHUNK * HEADS * 4;
    const size_t needed    = off_G     + (size_t)NCHUNK * CHUNK * CHUNK * 4;
    if (ws_size < needed) return;

    unsigned short* xb    = (unsigned short*)(ws + off_xb);
    unsigned short* wbin  = (unsigned short*)(ws + off_wbin);
    unsigned short* xbcd  = (unsigned short*)(ws + off_xbcd);
    unsigned short* xc    = (unsigned short*)(ws + off_xc);
    float* dtraw = (float*)(ws + off_dtraw);
    float* dtv   = (float*)(ws + off_dtv);
    float* dAc   = (float*)(ws + off_dAc);
    float* dAl   = (float*)(ws + off_dAl);
    float* G     = (float*)(ws + off_G);

    float* states      = (float*)d_out;
    unsigned short* z  = (unsigned short*)d_out;
    unsigned short* y  = xbcd;
    unsigned short* yb = xc;
    unsigned short* wob = wbin;

    { long n = (long)SEQ * DIMIN;
      k_convert<<<(unsigned)((n + 255) / 256), 256, 0, stream>>>(x, xb, n, n); }
    { long n = (long)WROWS * DIMIN, nsrc = (long)D_IN * DIMIN;
      k_convert<<<(unsigned)((n + 255) / 256), 256, 0, stream>>>(in_proj_w, wbin, n, nsrc); }
    k_gemm<1><<<dim3(XBCD_N / BN, SEQ / BM), 256, 0, stream>>>(
        xb, wbin + (size_t)HID * DIMIN, (void*)xbcd, DIMIN, XBCD_N, dtraw, 4352);
    { long n = (long)SEQ * CONV_DIM;
      k_conv<<<(unsigned)((n + 255) / 256), 256, 0, stream>>>(xbcd, conv_w, xc); }
    k_dt<<<dim3(NCHUNK, HEADS), 256, 0, stream>>>(dtraw, dt_bias, A_log, dtv, dAc, dAl);
    k_G<<<dim3(NCHUNK, CHUNK), 256, 0, stream>>>(xc, G);
    k_states<<<dim3(NCHUNK, HEADS), 256, 0, stream>>>(xc, dtv, dAc, dAl, states);
    k_scan<<<(HEADS * HEAD_DIM * STATE) / 256, 256, 0, stream>>>(states, dAl);
    k_ssd_y<<<dim3(NCHUNK, HEADS), 256, 0, stream>>>(xc, G, dtv, dAc, states, Dp, y);
    k_gemm<1><<<dim3(HID / BN, SEQ / BM), 256, 0, stream>>>(
        xb, wbin, (void*)z, DIMIN, HID, nullptr, 0);
    k_norm<<<SEQ, 256, 0, stream>>>(y, z, norm_w, yb);
    { long n = (long)DIMIN * HID;
      k_convert<<<(unsigned)((n + 255) / 256), 256, 0, stream>>>(out_proj_w, wob, n, n); }
    k_gemm<0><<<dim3(DIMIN / BN, SEQ / BM), 256, 0, stream>>>(
        yb, wob, d_out, HID, DIMIN, nullptr, 0);
}